// Round 1
// baseline (1000.159 us; speedup 1.0000x reference)
//
#include <hip/hip_runtime.h>

#define H 64

// --- CSR build ---------------------------------------------------------------

__global__ __launch_bounds__(256) void hist_kernel(const int* __restrict__ dst,
                                                   int* __restrict__ cnt, int E) {
  int e = blockIdx.x * 256 + threadIdx.x;
  if (e < E) atomicAdd(&cnt[dst[e]], 1);
}

// Single-block scan over N node counts -> exclusive rowptr, plus dinv = rsqrt(deg+1).
__global__ __launch_bounds__(1024) void scan_kernel(const int* __restrict__ cnt,
                                                    int* __restrict__ rowptr,
                                                    float* __restrict__ dinv, int N) {
  __shared__ int sdata[1024];
  int t = threadIdx.x;
  int chunk = (N + 1023) >> 10;
  int lo = t * chunk;
  int hi = min(lo + chunk, N);
  int s = 0;
  for (int i = lo; i < hi; ++i) s += cnt[i];
  sdata[t] = s;
  __syncthreads();
  // Hillis-Steele inclusive scan over 1024 partials
  for (int off = 1; off < 1024; off <<= 1) {
    int v = (t >= off) ? sdata[t - off] : 0;
    __syncthreads();
    sdata[t] += v;
    __syncthreads();
  }
  int run = (t == 0) ? 0 : sdata[t - 1];
  for (int i = lo; i < hi; ++i) {
    rowptr[i] = run;
    int c = cnt[i];
    run += c;
    dinv[i] = rsqrtf((float)(c + 1));  // +1 for the self-loop; always > 0
  }
  if (t == 0) rowptr[N] = sdata[1023];
}

__global__ __launch_bounds__(256) void fill_kernel(const int* __restrict__ src,
                                                   const int* __restrict__ dst,
                                                   const int* __restrict__ rowptr,
                                                   int* __restrict__ fill,
                                                   int* __restrict__ csr, int E) {
  int e = blockIdx.x * 256 + threadIdx.x;
  if (e >= E) return;
  int d = dst[e];
  int p = rowptr[d] + atomicAdd(&fill[d], 1);
  csr[p] = src[e];
}

// --- GEMM: out[r][c] = sum_k X[r][k] * W[k][c]  (+bias[c]) (*dinv[r]) --------
// 256 threads, 16 rows/block. lane = output col (64 cols), tid>>6 = row quad.
// W tile in LDS (K*64*4 B), X rows in LDS; xs reads are wave-broadcast,
// Ws reads are stride-1 (2-way LDS aliasing = free on gfx950).

template <int K, bool BIAS, bool SCALE>
__global__ __launch_bounds__(256) void gemm_kernel(const float* __restrict__ X,
                                                   const float* __restrict__ W,
                                                   const float* __restrict__ bias,
                                                   const float* __restrict__ dinv,
                                                   float* __restrict__ out, int N) {
  __shared__ __align__(16) float Ws[K * H];
  __shared__ __align__(16) float xs[16 * K];
  const int tid = threadIdx.x;
  const int c = tid & 63;
  const int rq = tid >> 6;  // 0..3
  const int row0 = blockIdx.x * 16;

  for (int i = tid; i < K * H; i += 256) Ws[i] = W[i];
  for (int i = tid; i < 16 * K; i += 256) {
    int r = row0 + i / K;
    xs[i] = (r < N) ? X[(size_t)r * K + (i % K)] : 0.f;
  }
  __syncthreads();

  float acc[4] = {0.f, 0.f, 0.f, 0.f};
  for (int k = 0; k < K; k += 4) {
    float4 xv[4];
#pragma unroll
    for (int u = 0; u < 4; ++u)
      xv[u] = *(const float4*)&xs[(rq * 4 + u) * K + k];
#pragma unroll
    for (int kk = 0; kk < 4; ++kk) {
      float w = Ws[(k + kk) * H + c];
      acc[0] = fmaf(((const float*)&xv[0])[kk], w, acc[0]);
      acc[1] = fmaf(((const float*)&xv[1])[kk], w, acc[1]);
      acc[2] = fmaf(((const float*)&xv[2])[kk], w, acc[2]);
      acc[3] = fmaf(((const float*)&xv[3])[kk], w, acc[3]);
    }
  }

#pragma unroll
  for (int u = 0; u < 4; ++u) {
    int r = row0 + rq * 4 + u;
    if (r < N) {
      float v = acc[u];
      if (BIAS) v += bias[c];
      if (SCALE) v *= dinv[r];
      out[(size_t)r * H + c] = v;
    }
  }
}

// --- Gather-aggregate: one wave per node, lane = channel ---------------------
// out[i][c] = relu(dinv[i] * (g[i][c] + sum_{e: dst=i} g[src_e][c]) + b[c])

__global__ __launch_bounds__(256) void gather_kernel(const float* __restrict__ g,
                                                     const int* __restrict__ rowptr,
                                                     const int* __restrict__ csr,
                                                     const float* __restrict__ dinv,
                                                     const float* __restrict__ bias,
                                                     float* __restrict__ out, int N) {
  int node = (blockIdx.x * 256 + threadIdx.x) >> 6;
  int c = threadIdx.x & 63;
  if (node >= N) return;

  float acc = g[(size_t)node * H + c];  // self-loop term
  int beg = rowptr[node];
  int end = rowptr[node + 1];
  for (int base = beg; base < end; base += 64) {
    int m = min(64, end - base);
    int idx = 0;
    if (c < m) idx = csr[base + c];  // one coalesced load covers up to 64 edges
    for (int j = 0; j < m; ++j) {
      int s = __shfl(idx, j, 64);    // wave-uniform broadcast of neighbor id
      acc += g[(size_t)s * H + c];   // 256B coalesced row read
    }
  }
  out[(size_t)node * H + c] = fmaxf(fmaf(dinv[node], acc, bias[c]), 0.f);
}

// --- Launch ------------------------------------------------------------------

extern "C" void kernel_launch(void* const* d_in, const int* in_sizes, int n_in,
                              void* d_out, int out_size, void* d_ws, size_t ws_size,
                              hipStream_t stream) {
  const float* x = (const float*)d_in[0];
  const int* ei = (const int*)d_in[1];
  const float* W_pre = (const float*)d_in[2];
  const float* b_pre = (const float*)d_in[3];
  const float* W1 = (const float*)d_in[4];
  const float* b1 = (const float*)d_in[5];
  const float* W2 = (const float*)d_in[6];
  const float* b2 = (const float*)d_in[7];

  const int IN = 128;
  const int N = in_sizes[0] / IN;
  const int E = in_sizes[1] / 2;
  const int* src = ei;       // edge_index[0]
  const int* dst = ei + E;   // edge_index[1]

  float* out = (float*)d_out;                 // output 0: final x  [N,64]
  float* ori = out + (size_t)N * H;           // output 1: ori_x    [N,64]

  // workspace carve (all 256B aligned)
  char* p = (char*)d_ws;
  auto take = [&](size_t bytes) {
    char* q = p;
    p += (bytes + 255) & ~(size_t)255;
    return q;
  };
  int* cnt = (int*)take((size_t)N * 4);
  int* fill = (int*)take((size_t)N * 4);
  int* rowptr = (int*)take(((size_t)N + 1) * 4);
  float* dinv = (float*)take((size_t)N * 4);
  int* csr = (int*)take((size_t)E * 4);
  float* g = (float*)take((size_t)N * H * 4);

  hipMemsetAsync(cnt, 0, (size_t)N * 4, stream);
  hipMemsetAsync(fill, 0, (size_t)N * 4, stream);

  int eb = (E + 255) / 256;
  hist_kernel<<<eb, 256, 0, stream>>>(dst, cnt, E);
  scan_kernel<<<1, 1024, 0, stream>>>(cnt, rowptr, dinv, N);
  fill_kernel<<<eb, 256, 0, stream>>>(src, dst, rowptr, fill, csr, E);

  int gb = (N + 15) / 16;
  // ori_x = x @ W_pre + b_pre  (written straight into output 1, reused as layer-1 input)
  gemm_kernel<128, true, false><<<gb, 256, 0, stream>>>(x, W_pre, b_pre, nullptr, ori, N);

  int nb = (N + 3) / 4;  // 4 waves/block, one node per wave
  // layer 1
  gemm_kernel<64, false, true><<<gb, 256, 0, stream>>>(ori, W1, nullptr, dinv, g, N);
  gather_kernel<<<nb, 256, 0, stream>>>(g, rowptr, csr, dinv, b1, out, N);
  // layer 2 (reads x1 from d_out, g fully computed before gather overwrites d_out)
  gemm_kernel<64, false, true><<<gb, 256, 0, stream>>>(out, W2, nullptr, dinv, g, N);
  gather_kernel<<<nb, 256, 0, stream>>>(g, rowptr, csr, dinv, b2, out, N);
}

// Round 2
// 490.746 us; speedup vs baseline: 2.0380x; 2.0380x over previous
//
#include <hip/hip_runtime.h>

#define H 64
#define STILE 2048  // scan tile: 256 threads x 8 elements

// --- CSR build ---------------------------------------------------------------

__global__ __launch_bounds__(256) void hist_kernel(const int* __restrict__ dst,
                                                   int* __restrict__ cnt, int E) {
  int e = blockIdx.x * 256 + threadIdx.x;
  if (e < E) atomicAdd(&cnt[dst[e]], 1);
}

// Pass 1: per-block sums of cnt (STILE elements per block).
__global__ __launch_bounds__(256) void scan_reduce_kernel(const int* __restrict__ cnt,
                                                          int* __restrict__ bsum, int N) {
  __shared__ int wsum[4];
  int t = threadIdx.x;
  int base = blockIdx.x * STILE + t * 8;
  int s = 0;
#pragma unroll
  for (int j = 0; j < 8; ++j) {
    int idx = base + j;
    if (idx < N) s += cnt[idx];
  }
#pragma unroll
  for (int off = 32; off > 0; off >>= 1) s += __shfl_down(s, off, 64);
  if ((t & 63) == 0) wsum[t >> 6] = s;
  __syncthreads();
  if (t == 0) bsum[blockIdx.x] = wsum[0] + wsum[1] + wsum[2] + wsum[3];
}

// Pass 2: one block scans the (<=1024) block sums -> exclusive offsets + grand total.
__global__ __launch_bounds__(1024) void scan_top_kernel(int* __restrict__ bsum, int nb,
                                                        int* __restrict__ totalp) {
  __shared__ int sd[1024];
  int t = threadIdx.x;
  int v = (t < nb) ? bsum[t] : 0;
  sd[t] = v;
  __syncthreads();
  for (int off = 1; off < 1024; off <<= 1) {
    int n = (t >= off) ? sd[t - off] : 0;
    __syncthreads();
    sd[t] += n;
    __syncthreads();
  }
  if (t < nb) bsum[t] = sd[t] - v;  // exclusive prefix
  if (t == 1023) *totalp = sd[1023];
}

// Pass 3: per-block exclusive scan -> rowptr, plus dinv = rsqrt(deg+1).
__global__ __launch_bounds__(256) void scan_final_kernel(const int* __restrict__ cnt,
                                                         const int* __restrict__ bsum,
                                                         int* __restrict__ rowptr,
                                                         float* __restrict__ dinv, int N) {
  __shared__ int woff[4];
  int t = threadIdx.x;
  int lane = t & 63;
  int w = t >> 6;
  int base = blockIdx.x * STILE + t * 8;
  int v[8];
  int s = 0;
#pragma unroll
  for (int j = 0; j < 8; ++j) {
    int idx = base + j;
    v[j] = (idx < N) ? cnt[idx] : 0;
    s += v[j];
  }
  int inc = s;  // inclusive wave scan of per-thread sums
#pragma unroll
  for (int off = 1; off < 64; off <<= 1) {
    int n = __shfl_up(inc, off, 64);
    if (lane >= off) inc += n;
  }
  if (lane == 63) woff[w] = inc;
  __syncthreads();
  int cross = 0;
  for (int ww = 0; ww < w; ++ww) cross += woff[ww];
  int off0 = bsum[blockIdx.x] + cross + (inc - s);  // exclusive offset for this thread
#pragma unroll
  for (int j = 0; j < 8; ++j) {
    int idx = base + j;
    if (idx < N) {
      rowptr[idx] = off0;
      dinv[idx] = rsqrtf((float)(v[j] + 1));  // +1 self-loop; always > 0
      off0 += v[j];
    }
  }
}

__global__ __launch_bounds__(256) void fill_kernel(const int* __restrict__ src,
                                                   const int* __restrict__ dst,
                                                   const int* __restrict__ rowptr,
                                                   int* __restrict__ fill,
                                                   int* __restrict__ csr, int E) {
  int e = blockIdx.x * 256 + threadIdx.x;
  if (e >= E) return;
  int d = dst[e];
  int p = rowptr[d] + atomicAdd(&fill[d], 1);
  csr[p] = src[e];
}

// --- GEMM: out[r][c] = sum_k X[r][k] * W[k][c]  (+bias[c]) (*dinv[r]) --------
// Grid-stride persistent blocks: W staged to LDS ONCE per block. 16 rows/tile,
// lane = output col, tid>>6 = row quad. k-loop unroll capped to keep VGPR low.

template <int K, bool BIAS, bool SCALE>
__global__ __launch_bounds__(256, 4) void gemm_kernel(const float* __restrict__ X,
                                                      const float* __restrict__ W,
                                                      const float* __restrict__ bias,
                                                      const float* __restrict__ dinv,
                                                      float* __restrict__ out, int N) {
  __shared__ __align__(16) float Ws[K * H];
  __shared__ __align__(16) float xs[16 * K];
  const int tid = threadIdx.x;
  const int c = tid & 63;
  const int rq = tid >> 6;  // 0..3

  for (int i = tid * 4; i < K * H; i += 1024)
    *(float4*)&Ws[i] = *(const float4*)&W[i];

  const int ntiles = (N + 15) >> 4;
  for (int tile = blockIdx.x; tile < ntiles; tile += gridDim.x) {
    const int row0 = tile << 4;
    __syncthreads();  // xs reuse from previous tile; also covers initial Ws load
    for (int i = tid * 4; i < 16 * K; i += 1024) {
      int r = row0 + i / K;
      float4 v = make_float4(0.f, 0.f, 0.f, 0.f);
      if (r < N) v = *(const float4*)&X[(size_t)r * K + (i % K)];
      *(float4*)&xs[i] = v;
    }
    __syncthreads();

    float acc0 = 0.f, acc1 = 0.f, acc2 = 0.f, acc3 = 0.f;
#pragma unroll 1
    for (int k = 0; k < K; k += 4) {
      float4 x0 = *(const float4*)&xs[(rq * 4 + 0) * K + k];
      float4 x1 = *(const float4*)&xs[(rq * 4 + 1) * K + k];
      float4 x2 = *(const float4*)&xs[(rq * 4 + 2) * K + k];
      float4 x3 = *(const float4*)&xs[(rq * 4 + 3) * K + k];
      float w0 = Ws[(k + 0) * H + c];
      float w1 = Ws[(k + 1) * H + c];
      float w2 = Ws[(k + 2) * H + c];
      float w3 = Ws[(k + 3) * H + c];
      acc0 = fmaf(x0.x, w0, fmaf(x0.y, w1, fmaf(x0.z, w2, fmaf(x0.w, w3, acc0))));
      acc1 = fmaf(x1.x, w0, fmaf(x1.y, w1, fmaf(x1.z, w2, fmaf(x1.w, w3, acc1))));
      acc2 = fmaf(x2.x, w0, fmaf(x2.y, w1, fmaf(x2.z, w2, fmaf(x2.w, w3, acc2))));
      acc3 = fmaf(x3.x, w0, fmaf(x3.y, w1, fmaf(x3.z, w2, fmaf(x3.w, w3, acc3))));
    }

    float accs[4] = {acc0, acc1, acc2, acc3};
#pragma unroll
    for (int u = 0; u < 4; ++u) {
      int r = row0 + rq * 4 + u;
      if (r < N) {
        float v = accs[u];
        if (BIAS) v += bias[c];
        if (SCALE) v *= dinv[r];
        out[(size_t)r * H + c] = v;
      }
    }
  }
}

// --- Gather-aggregate: one wave per node, lane = channel ---------------------
// out[i][c] = relu(dinv[i] * (g[i][c] + sum_{e: dst=i} g[src_e][c]) + b[c])

__global__ __launch_bounds__(256) void gather_kernel(const float* __restrict__ g,
                                                     const int* __restrict__ rowptr,
                                                     const int* __restrict__ csr,
                                                     const float* __restrict__ dinv,
                                                     const float* __restrict__ bias,
                                                     float* __restrict__ out, int N) {
  int node = (blockIdx.x * 256 + threadIdx.x) >> 6;
  int c = threadIdx.x & 63;
  if (node >= N) return;

  float acc = g[(size_t)node * H + c];  // self-loop term
  int beg = rowptr[node];
  int end = rowptr[node + 1];
  for (int base = beg; base < end; base += 64) {
    int m = min(64, end - base);
    int idx = 0;
    if (c < m) idx = csr[base + c];  // one coalesced load covers up to 64 edges
    for (int j = 0; j < m; ++j) {
      int s = __shfl(idx, j, 64);    // wave-uniform broadcast of neighbor id
      acc += g[(size_t)s * H + c];   // 256B coalesced row read
    }
  }
  out[(size_t)node * H + c] = fmaxf(fmaf(dinv[node], acc, bias[c]), 0.f);
}

// --- Launch ------------------------------------------------------------------

extern "C" void kernel_launch(void* const* d_in, const int* in_sizes, int n_in,
                              void* d_out, int out_size, void* d_ws, size_t ws_size,
                              hipStream_t stream) {
  const float* x = (const float*)d_in[0];
  const int* ei = (const int*)d_in[1];
  const float* W_pre = (const float*)d_in[2];
  const float* b_pre = (const float*)d_in[3];
  const float* W1 = (const float*)d_in[4];
  const float* b1 = (const float*)d_in[5];
  const float* W2 = (const float*)d_in[6];
  const float* b2 = (const float*)d_in[7];

  const int IN = 128;
  const int N = in_sizes[0] / IN;
  const int E = in_sizes[1] / 2;
  const int* src = ei;      // edge_index[0]
  const int* dst = ei + E;  // edge_index[1]

  float* out = (float*)d_out;        // output 0: final x  [N,64]
  float* ori = out + (size_t)N * H;  // output 1: ori_x    [N,64]

  char* p = (char*)d_ws;
  auto take = [&](size_t bytes) {
    char* q = p;
    p += (bytes + 255) & ~(size_t)255;
    return q;
  };
  int* cnt = (int*)take((size_t)N * 4);
  int* fill = (int*)take((size_t)N * 4);
  int* rowptr = (int*)take(((size_t)N + 1) * 4);
  float* dinv = (float*)take((size_t)N * 4);
  int* csr = (int*)take((size_t)E * 4);
  float* g = (float*)take((size_t)N * H * 4);
  int* bsum = (int*)take(1024 * 4);

  hipMemsetAsync(cnt, 0, (size_t)N * 4, stream);
  hipMemsetAsync(fill, 0, (size_t)N * 4, stream);

  int eb = (E + 255) / 256;
  int nscan = (N + STILE - 1) / STILE;  // 49 blocks at N=100k (must be <= 1024)
  hist_kernel<<<eb, 256, 0, stream>>>(dst, cnt, E);
  scan_reduce_kernel<<<nscan, 256, 0, stream>>>(cnt, bsum, N);
  scan_top_kernel<<<1, 1024, 0, stream>>>(bsum, nscan, rowptr + N);
  scan_final_kernel<<<nscan, 256, 0, stream>>>(cnt, bsum, rowptr, dinv, N);
  fill_kernel<<<eb, 256, 0, stream>>>(src, dst, rowptr, fill, csr, E);

  int ntiles = (N + 15) / 16;
  int gb = ntiles < 1024 ? ntiles : 1024;
  // ori_x = x @ W_pre + b_pre  (written straight into output 1, reused as layer-1 input)
  gemm_kernel<128, true, false><<<gb, 256, 0, stream>>>(x, W_pre, b_pre, nullptr, ori, N);

  int nb = (N + 3) / 4;  // 4 waves/block, one node per wave
  // layer 1
  gemm_kernel<64, false, true><<<gb, 256, 0, stream>>>(ori, W1, nullptr, dinv, g, N);
  gather_kernel<<<nb, 256, 0, stream>>>(g, rowptr, csr, dinv, b1, out, N);
  // layer 2 (reads x1 from d_out; g fully written before gather overwrites d_out)
  gemm_kernel<64, false, true><<<gb, 256, 0, stream>>>(out, W2, nullptr, dinv, g, N);
  gather_kernel<<<nb, 256, 0, stream>>>(g, rowptr, csr, dinv, b2, out, N);
}

// Round 3
// 439.986 us; speedup vs baseline: 2.2732x; 1.1154x over previous
//
#include <hip/hip_runtime.h>

#define H 64
#define STILE 2048  // scan tile: 256 threads x 8 elements

typedef __attribute__((ext_vector_type(8))) short short8;
typedef __attribute__((ext_vector_type(4))) float floatx4;
typedef __attribute__((ext_vector_type(8))) unsigned short ushort8v;
typedef __attribute__((ext_vector_type(4))) unsigned short ushort4v;

static __device__ __forceinline__ unsigned short f2bf(float f) {
  union { float f; unsigned u; } x{f};
  unsigned r = x.u + 0x7fffu + ((x.u >> 16) & 1u);  // RNE
  return (unsigned short)(r >> 16);
}
static __device__ __forceinline__ float bf2f(unsigned short u) {
  union { unsigned u; float f; } x{(unsigned)u << 16};
  return x.f;
}

// --- CSR build ---------------------------------------------------------------

__global__ __launch_bounds__(256) void hist_kernel(const int* __restrict__ dst,
                                                   int* __restrict__ cnt, int E) {
  int e = blockIdx.x * 256 + threadIdx.x;
  if (e < E) atomicAdd(&cnt[dst[e]], 1);
}

__global__ __launch_bounds__(256) void scan_reduce_kernel(const int* __restrict__ cnt,
                                                          int* __restrict__ bsum, int N) {
  __shared__ int wsum[4];
  int t = threadIdx.x;
  int base = blockIdx.x * STILE + t * 8;
  int s = 0;
#pragma unroll
  for (int j = 0; j < 8; ++j) {
    int idx = base + j;
    if (idx < N) s += cnt[idx];
  }
#pragma unroll
  for (int off = 32; off > 0; off >>= 1) s += __shfl_down(s, off, 64);
  if ((t & 63) == 0) wsum[t >> 6] = s;
  __syncthreads();
  if (t == 0) bsum[blockIdx.x] = wsum[0] + wsum[1] + wsum[2] + wsum[3];
}

__global__ __launch_bounds__(1024) void scan_top_kernel(int* __restrict__ bsum, int nb,
                                                        int* __restrict__ totalp) {
  __shared__ int sd[1024];
  int t = threadIdx.x;
  int v = (t < nb) ? bsum[t] : 0;
  sd[t] = v;
  __syncthreads();
  for (int off = 1; off < 1024; off <<= 1) {
    int n = (t >= off) ? sd[t - off] : 0;
    __syncthreads();
    sd[t] += n;
    __syncthreads();
  }
  if (t < nb) bsum[t] = sd[t] - v;  // exclusive prefix
  if (t == 1023) *totalp = sd[1023];
}

// rowptr + a second writable copy (wptr) for fill; dinv = rsqrt(deg+1).
__global__ __launch_bounds__(256) void scan_final_kernel(const int* __restrict__ cnt,
                                                         const int* __restrict__ bsum,
                                                         int* __restrict__ rowptr,
                                                         int* __restrict__ wptr,
                                                         float* __restrict__ dinv, int N) {
  __shared__ int woff[4];
  int t = threadIdx.x;
  int lane = t & 63;
  int w = t >> 6;
  int base = blockIdx.x * STILE + t * 8;
  int v[8];
  int s = 0;
#pragma unroll
  for (int j = 0; j < 8; ++j) {
    int idx = base + j;
    v[j] = (idx < N) ? cnt[idx] : 0;
    s += v[j];
  }
  int inc = s;
#pragma unroll
  for (int off = 1; off < 64; off <<= 1) {
    int n = __shfl_up(inc, off, 64);
    if (lane >= off) inc += n;
  }
  if (lane == 63) woff[w] = inc;
  __syncthreads();
  int cross = 0;
  for (int ww = 0; ww < w; ++ww) cross += woff[ww];
  int off0 = bsum[blockIdx.x] + cross + (inc - s);
#pragma unroll
  for (int j = 0; j < 8; ++j) {
    int idx = base + j;
    if (idx < N) {
      rowptr[idx] = off0;
      wptr[idx] = off0;
      dinv[idx] = rsqrtf((float)(v[j] + 1));  // +1 self-loop; always > 0
      off0 += v[j];
    }
  }
}

__global__ __launch_bounds__(256) void fill_kernel(const int* __restrict__ src,
                                                   const int* __restrict__ dst,
                                                   int* __restrict__ wptr,
                                                   int* __restrict__ csr, int E) {
  int e = blockIdx.x * 256 + threadIdx.x;
  if (e >= E) return;
  int p = atomicAdd(&wptr[dst[e]], 1);
  csr[p] = src[e];
}

// --- W -> bf16 B-fragment pack ----------------------------------------------
// Frag layout per MFMA 16x16x32_bf16 B operand: B[k=(l>>4)*8+j][n=l&15].
// Storage: frag[((w*KB + kb)*64 + l)*8 + j], w = col-quarter, kb = k-block of 32.
// Segments: W_pre (K=128, 8192 slots), W1 (K=64, 4096), W2 (K=64, 4096).

__global__ __launch_bounds__(256) void wprep_kernel(const float* __restrict__ Wpre,
                                                    const float* __restrict__ W1,
                                                    const float* __restrict__ W2,
                                                    unsigned short* __restrict__ frag) {
  int i = blockIdx.x * 256 + threadIdx.x;
  const float* W;
  int K, base;
  if (i < 8192) {
    W = Wpre; K = 128; base = 0;
  } else if (i < 12288) {
    W = W1; K = 64; base = 8192;
  } else if (i < 16384) {
    W = W2; K = 64; base = 12288;
  } else {
    return;
  }
  int s = i - base;
  int j = s & 7;
  int t = s >> 3;
  int l = t & 63;
  int t2 = t >> 6;
  int KB = K / 32;
  int kb = t2 % KB;
  int w = t2 / KB;
  int k = kb * 32 + ((l >> 4) & 3) * 8 + j;
  int n = w * 16 + (l & 15);
  frag[i] = f2bf(W[k * H + n]);
}

// --- MFMA GEMM: out[r][c] = sum_k X[r][k]*W[k][c] (+bias[c]) (*dinv[r]) ------
// Block = 256 thr = 4 waves; tile = 16 rows x 64 cols; wave w owns cols [16w,16w+16).
// X rows converted to bf16 A-frags in LDS; B-frags preloaded to regs from packed W.

template <int K, bool BIAS, bool SCALE, typename InT, typename OutT>
__global__ __launch_bounds__(256) void mfma_gemm_kernel(
    const InT* __restrict__ X, const unsigned short* __restrict__ Wfrag,
    const float* __restrict__ bias, const float* __restrict__ dinv,
    OutT* __restrict__ out, int N) {
  constexpr int KB = K / 32;
  __shared__ unsigned short As[KB * 64 * 8];  // A-frags [kb][lane][8]
  __shared__ float dinv_s[16];
  const int tid = threadIdx.x;
  const int w = tid >> 6;
  const int lane = tid & 63;
  const int row0 = blockIdx.x * 16;

  // ---- stage A tile (16 x K) as bf16 fragments ----
  if constexpr (K == 128) {
    int kb = tid >> 6;  // 0..3
    int l = tid & 63;
    int m = l & 15;
    int k0 = kb * 32 + (l >> 4) * 8;
    int r = row0 + m;
    ushort8v v = {0, 0, 0, 0, 0, 0, 0, 0};
    if (r < N) {
      if constexpr (sizeof(InT) == 4) {
        const float* xp = (const float*)&X[(size_t)r * K + k0];
        float4 a = *(const float4*)xp;
        float4 b = *(const float4*)(xp + 4);
        v = ushort8v{f2bf(a.x), f2bf(a.y), f2bf(a.z), f2bf(a.w),
                     f2bf(b.x), f2bf(b.y), f2bf(b.z), f2bf(b.w)};
      } else {
        v = *(const ushort8v*)&X[(size_t)r * K + k0];
      }
    }
    *(ushort8v*)&As[(kb * 64 + l) * 8] = v;
  } else {  // K == 64
    int kb = tid >> 7;  // 0..1
    int hh = tid & 127;
    int l = hh >> 1;
    int j0 = (tid & 1) * 4;
    int m = l & 15;
    int k0 = kb * 32 + (l >> 4) * 8 + j0;
    int r = row0 + m;
    ushort4v v = {0, 0, 0, 0};
    if (r < N) {
      if constexpr (sizeof(InT) == 4) {
        float4 a = *(const float4*)&X[(size_t)r * K + k0];
        v = ushort4v{f2bf(a.x), f2bf(a.y), f2bf(a.z), f2bf(a.w)};
      } else {
        v = *(const ushort4v*)&X[(size_t)r * K + k0];
      }
    }
    *(ushort4v*)&As[(kb * 64 + l) * 8 + j0] = v;
  }
  if (SCALE && tid < 16) dinv_s[tid] = (row0 + tid < N) ? dinv[row0 + tid] : 1.f;

  // ---- preload this wave's B fragments (regs; no LDS) ----
  short8 bfrag[KB];
  const unsigned short* wf = &Wfrag[((size_t)(w * KB) * 64 + lane) * 8];
#pragma unroll
  for (int kb = 0; kb < KB; ++kb) bfrag[kb] = *(const short8*)&wf[kb * 512];

  __syncthreads();

  floatx4 acc = {0.f, 0.f, 0.f, 0.f};
#pragma unroll
  for (int kb = 0; kb < KB; ++kb) {
    short8 a = *(const short8*)&As[(kb * 64 + lane) * 8];
    acc = __builtin_amdgcn_mfma_f32_16x16x32_bf16(a, bfrag[kb], acc, 0, 0, 0);
  }

  // ---- epilogue: D col=lane&15, row=(lane>>4)*4+reg ----
  int c = w * 16 + (lane & 15);
  int q = lane >> 4;
  float bv = BIAS ? bias[c] : 0.f;
#pragma unroll
  for (int r = 0; r < 4; ++r) {
    int row = row0 + q * 4 + r;
    if (row < N) {
      float v = acc[r];
      if (BIAS) v += bv;
      if (SCALE) v *= dinv_s[q * 4 + r];
      if constexpr (sizeof(OutT) == 2)
        out[(size_t)row * H + c] = (OutT)f2bf(v);
      else
        out[(size_t)row * H + c] = v;
    }
  }
}

// --- Gather-aggregate: one wave per node, lane = channel ---------------------
// out[i][c] = relu(dinv[i] * (g[i][c] + sum_{e: dst=i} g[src_e][c]) + b[c])
// g is bf16 (128 B/row = one cache line per edge); accumulate fp32.

template <typename OutT>
__global__ __launch_bounds__(256) void gather_kernel(const unsigned short* __restrict__ g,
                                                     const int* __restrict__ rowptr,
                                                     const int* __restrict__ csr,
                                                     const float* __restrict__ dinv,
                                                     const float* __restrict__ bias,
                                                     OutT* __restrict__ out, int N) {
  int node = (blockIdx.x * 256 + threadIdx.x) >> 6;
  int c = threadIdx.x & 63;
  if (node >= N) return;

  float acc = bf2f(g[(size_t)node * H + c]);  // self-loop term
  int beg = rowptr[node];
  int end = rowptr[node + 1];
  for (int base = beg; base < end; base += 64) {
    int m = min(64, end - base);
    int idx = 0;
    if (c < m) idx = csr[base + c];  // one coalesced load covers up to 64 edges
    for (int j = 0; j < m; ++j) {
      int s = __shfl(idx, j, 64);               // wave-uniform neighbor id
      acc += bf2f(g[(size_t)s * H + c]);        // 128 B coalesced row read
    }
  }
  float v = fmaxf(fmaf(dinv[node], acc, bias[c]), 0.f);
  if constexpr (sizeof(OutT) == 2)
    out[(size_t)node * H + c] = (OutT)f2bf(v);
  else
    out[(size_t)node * H + c] = v;
}

// --- Launch ------------------------------------------------------------------

extern "C" void kernel_launch(void* const* d_in, const int* in_sizes, int n_in,
                              void* d_out, int out_size, void* d_ws, size_t ws_size,
                              hipStream_t stream) {
  const float* x = (const float*)d_in[0];
  const int* ei = (const int*)d_in[1];
  const float* W_pre = (const float*)d_in[2];
  const float* b_pre = (const float*)d_in[3];
  const float* W1 = (const float*)d_in[4];
  const float* b1 = (const float*)d_in[5];
  const float* W2 = (const float*)d_in[6];
  const float* b2 = (const float*)d_in[7];

  const int IN = 128;
  const int N = in_sizes[0] / IN;
  const int E = in_sizes[1] / 2;
  const int* src = ei;      // edge_index[0]
  const int* dst = ei + E;  // edge_index[1]

  float* out = (float*)d_out;        // output 0: final x  [N,64]
  float* ori = out + (size_t)N * H;  // output 1: ori_x    [N,64]

  char* p = (char*)d_ws;
  auto take = [&](size_t bytes) {
    char* q = p;
    p += (bytes + 255) & ~(size_t)255;
    return q;
  };
  int* rowptr = (int*)take(((size_t)N + 1) * 4);
  float* dinv = (float*)take((size_t)N * 4);
  int* csr = (int*)take((size_t)E * 4);
  unsigned short* g = (unsigned short*)take((size_t)N * H * 2);
  unsigned short* wfrag = (unsigned short*)take(16384 * 2);
  int* bsum = (int*)take(1024 * 4);
  // x1b region overlaps cnt+wptr (dead before gather-1 writes x1b)
  char* ubase = p;
  unsigned short* x1b = (unsigned short*)take((size_t)N * H * 2);
  int* cnt = (int*)ubase;
  int* wptr = (int*)(ubase + (((size_t)N * 4 + 255) & ~(size_t)255));

  hipMemsetAsync(cnt, 0, (size_t)N * 4, stream);

  int eb = (E + 255) / 256;
  int nscan = (N + STILE - 1) / STILE;  // 49 blocks at N=100k (must be <= 1024)
  hist_kernel<<<eb, 256, 0, stream>>>(dst, cnt, E);
  scan_reduce_kernel<<<nscan, 256, 0, stream>>>(cnt, bsum, N);
  scan_top_kernel<<<1, 1024, 0, stream>>>(bsum, nscan, rowptr + N);
  scan_final_kernel<<<nscan, 256, 0, stream>>>(cnt, bsum, rowptr, wptr, dinv, N);
  fill_kernel<<<eb, 256, 0, stream>>>(src, dst, wptr, csr, E);
  wprep_kernel<<<64, 256, 0, stream>>>(W_pre, W1, W2, wfrag);

  int gb = (N + 15) / 16;
  int nb = (N + 3) / 4;  // gather: 4 waves/block, one node per wave

  // ori_x = x @ W_pre + b_pre  (fp32, straight into output slot 1)
  mfma_gemm_kernel<128, true, false, float, float>
      <<<gb, 256, 0, stream>>>(x, wfrag, b_pre, nullptr, ori, N);
  // layer 1: g = (ori @ W1) * dinv   (bf16)
  mfma_gemm_kernel<64, false, true, float, unsigned short>
      <<<gb, 256, 0, stream>>>(ori, wfrag + 8192, nullptr, dinv, g, N);
  gather_kernel<unsigned short><<<nb, 256, 0, stream>>>(g, rowptr, csr, dinv, b1, x1b, N);
  // layer 2: g = (x1 @ W2) * dinv    (bf16 in, bf16 out)
  mfma_gemm_kernel<64, false, true, unsigned short, unsigned short>
      <<<gb, 256, 0, stream>>>(x1b, wfrag + 12288, nullptr, dinv, g, N);
  gather_kernel<float><<<nb, 256, 0, stream>>>(g, rowptr, csr, dinv, b2, out, N);
}